// Round 4
// baseline (706.927 us; speedup 1.0000x reference)
//
#include <hip/hip_runtime.h>
#include <hip/hip_bf16.h>

#define B_ROWS 16384
#define KDIM   2048   // D + H
#define NDIM   5120   // 5*H
#define HDIM   1024

// ---- fused GEMM geometry: 256 x 320 tile (320 = 5 gates x 64 h), BK=32 ----
#define BM 256
#define BN 320
#define BK 32
#define NKT (KDIM / BK)             // 64 K-tiles
#define A_BYTES (BM * BK * 2)       // 16384
#define W_BYTES (BN * BK * 2)       // 20480
#define BUFSZ   (A_BYTES + W_BYTES) // 36864
#define NBUF  4
#define LDS_BYTES (NBUF * BUFSZ)    // 147456 dynamic LDS (opt-in)

typedef __attribute__((ext_vector_type(8))) short short8;
typedef __attribute__((ext_vector_type(4))) float f32x4;

__device__ __forceinline__ void async_cp16(const void* g, void* l) {
  __builtin_amdgcn_global_load_lds(
      (const __attribute__((address_space(1))) void*)g,
      (__attribute__((address_space(3))) void*)l,
      16, 0, 0);
}

// ---------------------------------------------------------------------------
// dtype probe: x is N(0,1). If stored bf16, no 16-bit word has exponent
// field >= 137 (|v| >= 2^10). If stored fp32, half the words are uniform
// mantissa noise -> ~46% exceed it. flag=1 -> fp32 inputs, flag=0 -> bf16.
// ---------------------------------------------------------------------------
__global__ void detect_dtype(const unsigned short* __restrict__ p, int* flag) {
  __shared__ int cnt;
  if (threadIdx.x == 0) cnt = 0;
  __syncthreads();
  int h = 0;
  for (int i = threadIdx.x; i < 2048; i += 256) {
    int e = (p[i] >> 7) & 0xFF;
    if (e >= 137) h++;
  }
  atomicAdd(&cnt, h);
  __syncthreads();
  if (threadIdx.x == 0) *flag = (cnt >= 4) ? 1 : 0;
}

// ---------------------------------------------------------------------------
// pack rows [rbase, rbase+rows) of fp32 (s0|s1) -> bf16 [rows,2048].
// No-op when inputs are already bf16 (flag==0).
// ---------------------------------------------------------------------------
__global__ void pack_pair_f32(const float* __restrict__ s0, const float* __restrict__ s1,
                              __hip_bfloat16* __restrict__ dst, const int* __restrict__ flag,
                              long rbase, long total) {
  if (*flag == 0) return;
  long idx = ((long)blockIdx.x * blockDim.x + threadIdx.x) * 8;
  if (idx >= total) return;
  int  k = (int)(idx & (KDIM - 1));
  long r = (idx >> 11) + rbase;
  const float* s = (k < 1024) ? (s0 + r * 1024 + k) : (s1 + r * 1024 + (k - 1024));
  float4 v0 = ((const float4*)s)[0];
  float4 v1 = ((const float4*)s)[1];
  union { short8 v; __hip_bfloat16 e[8]; } u;
  u.e[0] = __float2bfloat16(v0.x); u.e[1] = __float2bfloat16(v0.y);
  u.e[2] = __float2bfloat16(v0.z); u.e[3] = __float2bfloat16(v0.w);
  u.e[4] = __float2bfloat16(v1.x); u.e[5] = __float2bfloat16(v1.y);
  u.e[6] = __float2bfloat16(v1.z); u.e[7] = __float2bfloat16(v1.w);
  *(short8*)(dst + idx) = u.v;
}

// ---------------------------------------------------------------------------
// Fused GEMM + LSTM epilogue. 256x320 tile, BK=32, 4 LDS buffers, depth-3
// counted-vmcnt prefetch (110 KB in flight per CU; never drained in loop).
//
// W column permutation at STAGING: instr j (=wg*5+g, 0..19) covers tile rows
// [wg*80+g*16, +16)  <-  W rows g*1024 + h0 + wg*16 + t. So wave wn's 5
// N-frags are the 5 gates of h = h0 + wn*16 + (lane&15): LSTM update is
// lane-local in acc[mi][g][r]. No G round-trip.
//
// LDS swizzle (round-2-verified, SQ_LDS_BANK_CONFLICT=0): 64-B rows, slot
// chunk sc at row sr holds data chunk sc ^ ((sr>>1)&3). Staged via
// pre-swizzled global source (lane-const (l&3)^((l>>3)&3)); read with
// lane-const swz = ((l>>4)^((frow>>1)&3))<<4.
//
// Waves 0-3 stage 3 W-instr (5 total, vmcnt(15)); waves 4-7 stage 2
// (4 total, vmcnt(12)) -- wave-uniform branch, exact counted waits.
//
// XCD swizzle (T1, bijective): same-m blocks (sharing the A panel)
// colocate per XCD for L2 reuse.
// ---------------------------------------------------------------------------
__global__ __launch_bounds__(512, 2) void gemm_fused(
    const __hip_bfloat16* __restrict__ Abf, const __hip_bfloat16* __restrict__ Wbf,
    const void* __restrict__ xr, const void* __restrict__ hr,
    const void* __restrict__ Wxr, const void* __restrict__ Uhr,
    const void* __restrict__ cpr, const void* __restrict__ dwr,
    const void* __restrict__ bxr, const void* __restrict__ bhr,
    float* __restrict__ out, const int* __restrict__ flag, int row_base) {
  extern __shared__ char lds[];

  const int tid = threadIdx.x;
  const int w   = tid >> 6;     // wave 0..7
  const int l   = tid & 63;

  // XCD-aware block swizzle: n-fastest within each XCD's contiguous run
  const int nb  = gridDim.x;          // 16 * (rows/256), divisible by 8
  const int q8  = nb >> 3;
  const int sw  = (blockIdx.x & 7) * q8 + (blockIdx.x >> 3);
  const int m0l = (sw >> 4) * BM;     // chunk-local row base
  const int h0  = (sw & 15) * 64;     // h-group base (16 groups)

  const int wm = w >> 2;   // 0..1
  const int wn = w & 3;    // 0..3

  const int fl = *flag;
  const int dc = (l & 3) ^ ((l >> 3) & 3);   // staged data chunk (lane-const)

  // --- A staging: 16 instr/block = 2/wave. Instr i covers tile rows
  //     w*32 + i*16 + (l>>2), data chunk dc.
  const __hip_bfloat16 *srcA0, *srcA1;
  long dA;
  {
    const int r0 = m0l + w * 32 + (l >> 2);
    if (fl) {
      srcA0 = Abf + (long)r0 * KDIM + dc * 8;
      srcA1 = Abf + (long)(r0 + 16) * KDIM + dc * 8;
      dA = 1024;
    } else {
      srcA0 = (const __hip_bfloat16*)xr + (long)(row_base + r0) * 1024 + dc * 8;
      srcA1 = (const __hip_bfloat16*)xr + (long)(row_base + r0 + 16) * 1024 + dc * 8;
      dA = (const __hip_bfloat16*)hr - (const __hip_bfloat16*)xr;
    }
  }

  // --- W staging: 20 instr/block. waves 0-3: j = 3w..3w+2; waves 4-7:
  //     j = 2w+4, 2w+5. Instr j: wg=j/5, g=j%5, source W row
  //     g*1024 + h0 + wg*16 + (l>>2), data chunk dc.
  const bool has3 = (w < 4);
  const int  jw0  = has3 ? (3 * w)     : (2 * w + 4);
  const int  jw1  = has3 ? (3 * w + 1) : (2 * w + 5);
  const int  jw2  = has3 ? (3 * w + 2) : (2 * w + 5);  // dup when unused
  const __hip_bfloat16 *srcW0, *srcW1, *srcW2;
  long dW;
  {
    const __hip_bfloat16* wbase;
    long strW;
    if (fl) { wbase = Wbf; strW = KDIM; dW = 1024; }
    else {
      wbase = (const __hip_bfloat16*)Wxr; strW = 1024;
      dW = (const __hip_bfloat16*)Uhr - (const __hip_bfloat16*)Wxr;
    }
    const int j0g = jw0 % 5, j0w = jw0 / 5;
    const int j1g = jw1 % 5, j1w = jw1 / 5;
    const int j2g = jw2 % 5, j2w = jw2 / 5;
    srcW0 = wbase + ((long)j0g * 1024 + h0 + j0w * 16 + (l >> 2)) * strW + dc * 8;
    srcW1 = wbase + ((long)j1g * 1024 + h0 + j1w * 16 + (l >> 2)) * strW + dc * 8;
    srcW2 = wbase + ((long)j2g * 1024 + h0 + j2w * 16 + (l >> 2)) * strW + dc * 8;
  }

#define STAGE(T) do {                                                        \
    const int  b_  = (T) & 3;                                                \
    const int  k0_ = (T) * BK;                                               \
    const long koA_ = (k0_ < 1024) ? (long)k0_ : (dA + (k0_ - 1024));        \
    const long koW_ = (k0_ < 1024) ? (long)k0_ : (dW + (k0_ - 1024));        \
    char* lb_ = lds + b_ * BUFSZ;                                            \
    async_cp16(srcA0 + koA_, lb_ + w * 2048 + l * 16);                       \
    async_cp16(srcA1 + koA_, lb_ + w * 2048 + 1024 + l * 16);                \
    async_cp16(srcW0 + koW_, lb_ + A_BYTES + jw0 * 1024 + l * 16);           \
    async_cp16(srcW1 + koW_, lb_ + A_BYTES + jw1 * 1024 + l * 16);           \
    if (has3)                                                                \
      async_cp16(srcW2 + koW_, lb_ + A_BYTES + jw2 * 1024 + l * 16);         \
  } while (0)

  f32x4 acc[8][5] = {};
  const int frow  = l & 15;
  const int swz   = ((l >> 4) ^ ((frow >> 1) & 3)) << 4;  // lane-const
  const int aoff0 = (wm * 128 + frow) * 64;               // A row byte base
  const int woff0 = A_BYTES + (wn * 80 + frow) * 64;      // W row byte base

#define COMPUTE(T) do {                                                      \
    const char* ba_ = lds + ((T) & 3) * BUFSZ;                               \
    short8 af_[8], wf_[5];                                                   \
    _Pragma("unroll")                                                        \
    for (int nj = 0; nj < 5; ++nj)                                           \
      wf_[nj] = *(const short8*)(ba_ + woff0 + nj * 1024 + swz);             \
    _Pragma("unroll")                                                        \
    for (int mi = 0; mi < 8; ++mi)                                           \
      af_[mi] = *(const short8*)(ba_ + aoff0 + mi * 1024 + swz);             \
    __builtin_amdgcn_s_setprio(1);                                           \
    _Pragma("unroll")                                                        \
    for (int mi = 0; mi < 8; ++mi)                                           \
      _Pragma("unroll")                                                      \
      for (int nj = 0; nj < 5; ++nj)                                         \
        acc[mi][nj] = __builtin_amdgcn_mfma_f32_16x16x32_bf16(               \
            af_[mi], wf_[nj], acc[mi][nj], 0, 0, 0);                         \
    __builtin_amdgcn_s_setprio(0);                                           \
  } while (0)

  STAGE(0); STAGE(1); STAGE(2);

  // main loop: depth-3 prefetch; per-wave exact counted vmcnt, never 0
  for (int t = 0; t < NKT - 3; ++t) {
    __builtin_amdgcn_s_barrier();            // all waves done reading buf[(t+3)&3]
    __builtin_amdgcn_sched_barrier(0);
    STAGE(t + 3);
    if (has3) { asm volatile("s_waitcnt vmcnt(15)" ::: "memory"); }
    else      { asm volatile("s_waitcnt vmcnt(12)" ::: "memory"); }
    __builtin_amdgcn_sched_barrier(0);
    __builtin_amdgcn_s_barrier();            // tile t visible to all waves
    __builtin_amdgcn_sched_barrier(0);
    COMPUTE(t);
  }
  // tail: drain
  for (int t = NKT - 3; t < NKT; ++t) {
    __builtin_amdgcn_s_barrier();
    asm volatile("s_waitcnt vmcnt(0)" ::: "memory");
    __builtin_amdgcn_sched_barrier(0);
    __builtin_amdgcn_s_barrier();
    __builtin_amdgcn_sched_barrier(0);
    COMPUTE(t);
  }

#undef STAGE
#undef COMPUTE

  // ---- fused LSTM epilogue: all 5 gates of h are lane-local ----
  // C layout (m89): col = lane&15 -> gate frag nj = gate g; row = (l>>4)*4 + r
  const int hh = h0 + wn * 16 + frow;     // global h index (0..1023)
  float bsum[5];
#pragma unroll
  for (int g = 0; g < 5; ++g) {
    if (fl) {
      bsum[g] = ((const float*)bxr)[g * 1024 + hh] + ((const float*)bhr)[g * 1024 + hh];
    } else {
      bsum[g] = __bfloat162float(((const __hip_bfloat16*)bxr)[g * 1024 + hh])
              + __bfloat162float(((const __hip_bfloat16*)bhr)[g * 1024 + hh]);
    }
  }
  const long orow0 = (long)row_base + m0l + wm * 128 + (l >> 4) * 4;
  float* outc = out + (long)B_ROWS * HDIM;
#pragma unroll
  for (int mi = 0; mi < 8; ++mi) {
#pragma unroll
    for (int r = 0; r < 4; ++r) {
      const long idx = (orow0 + mi * 16 + r) * HDIM + hh;
      float cp, dv;
      if (fl) {
        cp = ((const float*)cpr)[idx];
        dv = ((const float*)dwr)[idx];
      } else {
        cp = __bfloat162float(((const __hip_bfloat16*)cpr)[idx]);
        dv = __bfloat162float(((const __hip_bfloat16*)dwr)[idx]);
      }
      const float gi = acc[mi][0][r] + bsum[0];
      const float gf = acc[mi][1][r] + bsum[1];
      const float go = acc[mi][2][r] + bsum[2];
      const float gc = acc[mi][3][r] + bsum[3];
      const float gs = acc[mi][4][r] + bsum[4];
      const float it = 1.f / (1.f + __expf(-gi));
      const float ft = 1.f / (1.f + __expf(-gf));
      const float ot = 1.f / (1.f + __expf(-go));
      const float ch = tanhf(gc);
      const float st = (1.f / (1.f + __expf(-gs))) * dv;
      const float ct = ft * cp + it * ch * st;
      out[idx]  = ot * tanhf(ct);
      outc[idx] = ct;
    }
  }
}

// ---------------------------------------------------------------------------
extern "C" void kernel_launch(void* const* d_in, const int* in_sizes, int n_in,
                              void* d_out, int out_size, void* d_ws, size_t ws_size,
                              hipStream_t stream) {
  const void* x      = d_in[0];
  const void* h_prev = d_in[1];
  const void* c_prev = d_in[2];
  const void* dw     = d_in[3];
  const void* Wx     = d_in[4];
  const void* bx     = d_in[5];
  const void* Uh     = d_in[6];
  const void* bh     = d_in[7];

  // one-time opt-in to 144 KiB dynamic LDS (host-side, graph-safe)
  static int lds_attr_done = 0;
  if (!lds_attr_done) {
    hipFuncSetAttribute((const void*)gemm_fused,
                        hipFuncAttributeMaxDynamicSharedMemorySize, LDS_BYTES);
    lds_attr_done = 1;
  }

  // chunk count chosen from ws_size (host-constant -> graph-safe)
  const size_t wbf_bytes = (size_t)NDIM * KDIM * 2;  // 20 MiB
  int nc = 32;
  for (int c = 1; c <= 32; c <<= 1) {
    size_t need = 256 + wbf_bytes
                + (size_t)(B_ROWS / c) * KDIM * 2;   // Abf chunk
    if (need <= ws_size) { nc = c; break; }
  }
  const long rows = B_ROWS / nc;

  char* ws = (char*)d_ws;
  int* flag = (int*)ws;
  __hip_bfloat16* Wbf = (__hip_bfloat16*)(ws + 256);
  __hip_bfloat16* Abf = (__hip_bfloat16*)(ws + 256 + wbf_bytes);

  detect_dtype<<<1, 256, 0, stream>>>((const unsigned short*)x, flag);

  pack_pair_f32<<<(int)(((long)NDIM * KDIM) / 2048), 256, 0, stream>>>(
      (const float*)Wx, (const float*)Uh, Wbf, flag, 0, (long)NDIM * KDIM);

  for (int c = 0; c < nc; ++c) {
    long rbase = c * rows;
    pack_pair_f32<<<(int)rows, 256, 0, stream>>>(
        (const float*)x, (const float*)h_prev, Abf, flag, rbase, rows * KDIM);
    const int nblocks = (int)(16 * (rows / BM));   // divisible by 8
    gemm_fused<<<nblocks, 512, LDS_BYTES, stream>>>(
        Abf, Wbf, x, h_prev, Wx, Uh, c_prev, dw, bx, bh,
        (float*)d_out, flag, (int)rbase);
  }
}